// Round 1
// 65.537 us; speedup vs baseline: 1.2252x; 1.2252x over previous
//
#include <hip/hip_runtime.h>

#define BB 384
#define DD 256           // floats per row; 64 float4
#define F4 (DD / 4)      // 64
#define APB 2            // anchors per block
#define NBLK (BB / APB)  // 192 blocks
#define NT 512           // 8 waves/block -> 1536 waves on 1024 SIMDs
#define MARGIN 0.2f

// ---------------------------------------------------------------------------
// Fused kernel: one block (512 threads) per APB=2 anchors.
// Dist phase: 8 waves x 48 rows, 4 rows/iter, unroll 2 => 8 float4 loads in
// flight per wave. lane = 16*rr + dd; one instruction reads float4 f=16k+dd
// of rows b0+rr (4 contiguous 256B segments). Anchor fragments in registers;
// 16-lane shfl_xor butterfly reduces each row's diff^2 partials.
// Triplet phase: block halves process the two anchors CONCURRENTLY
// (tid<256 -> anchor a0, tid>=256 -> anchor a0+1). Positive thresholds
// (margin + d[a,p]) precomputed into s_t during the list build.
// ---------------------------------------------------------------------------
__global__ __launch_bounds__(NT) void triplet_fused_kernel(
    const float* __restrict__ x,
    const int* __restrict__ labels,
    double* __restrict__ partial_num,
    double* __restrict__ partial_den) {
    __shared__ int    s_lab[BB];
    __shared__ float  s_d[APB][BB];
    __shared__ float  s_t[APB][BB];   // margin + d[a, p] for each positive
    __shared__ int    s_np[APB], s_cnt[APB];
    __shared__ double s_red[8];

    const int tid  = threadIdx.x;
    const int wave = tid >> 6;    // 0..7
    const int lane = tid & 63;
    const int rr   = lane >> 4;   // row-within-quad: 0..3
    const int dd   = lane & 15;   // dim-segment lane: 0..15
    const int a0   = blockIdx.x * APB;

    const float4* x4 = reinterpret_cast<const float4*>(x);

    for (int i = tid; i < BB; i += NT) s_lab[i] = labels[i];

    // Anchor fragments in registers: xa[j][k] = float4 f = 16k + dd of row a0+j.
    float4 xa[APB][4];
#pragma unroll
    for (int j = 0; j < APB; ++j)
#pragma unroll
        for (int k = 0; k < 4; ++k)
            xa[j][k] = x4[(a0 + j) * F4 + k * 16 + dd];

    // ---- dist rows: each wave covers 48 rows, 4 rows per iteration ----
    const int rbeg = wave * 48;
#pragma unroll 2
    for (int b0 = rbeg; b0 < rbeg + 48; b0 += 4) {
        const int b = b0 + rr;
        float4 row[4];
#pragma unroll
        for (int k = 0; k < 4; ++k)
            row[k] = x4[b * F4 + k * 16 + dd];

        float s[APB];
#pragma unroll
        for (int j = 0; j < APB; ++j) {
            float sx = 0.f, sy = 0.f, sz = 0.f, sw = 0.f;
#pragma unroll
            for (int k = 0; k < 4; ++k) {
                float dx = row[k].x - xa[j][k].x;
                float dy = row[k].y - xa[j][k].y;
                float dz = row[k].z - xa[j][k].z;
                float dw = row[k].w - xa[j][k].w;
                sx += dx * dx;
                sy += dy * dy;
                sz += dz * dz;
                sw += dw * dw;
            }
            s[j] = (sx + sy) + (sz + sw);
        }
        // 16-lane butterfly (stays within the rr segment for masks 1,2,4,8)
#pragma unroll
        for (int mask = 1; mask < 16; mask <<= 1)
#pragma unroll
            for (int j = 0; j < APB; ++j)
                s[j] += __shfl_xor(s[j], mask, 64);

        if (dd == 0) s_d[0][b] = s[0];
        if (dd == 1) s_d[1][b] = s[1];
    }

    // ---- triplet phase: block halves handle the two anchors concurrently ----
    const int half = tid >> 8;    // 0 or 1 -> anchor index within block
    const int t2   = tid & 255;   // thread index within half
    const int a    = a0 + half;

    if (t2 == 0) { s_np[half] = 0; s_cnt[half] = 0; }
    __syncthreads();  // covers s_d writes, s_lab loads, and the inits

    const int la = s_lab[a];
    const float* dj = s_d[half];
    for (int i = t2; i < BB; i += 256) {
        if (s_lab[i] == la) {
            atomicAdd(&s_cnt[half], 1);
            if (i > a) {
                int k = atomicAdd(&s_np[half], 1);
                s_t[half][k] = MARGIN + dj[i];
            }
        }
    }
    __syncthreads();

    const int np  = s_np[half];
    const int cnt = s_cnt[half];

    double num_local = 0.0;
    for (int n = t2; n < BB; n += 256) {
        if (s_lab[n] != la) {
            const float dn = dj[n];
            for (int pi = 0; pi < np; ++pi) {
                float l = s_t[half][pi] - dn;
                if (l > 0.f) num_local += (double)l;
            }
        }
    }

    for (int off = 32; off > 0; off >>= 1)
        num_local += __shfl_down(num_local, off, 64);
    if (lane == 0) s_red[wave] = num_local;
    __syncthreads();

    if (tid == 0) {
        double tot = (s_red[0] + s_red[1]) + (s_red[2] + s_red[3]);
        partial_num[a] = tot * (double)cnt;
        partial_den[a] = (double)cnt * (double)np * (double)(BB - cnt);
    } else if (tid == 256) {
        double tot = (s_red[4] + s_red[5]) + (s_red[6] + s_red[7]);
        partial_num[a] = tot * (double)cnt;
        partial_den[a] = (double)cnt * (double)np * (double)(BB - cnt);
    }
}

// ---------------------------------------------------------------------------
// Finalize: reduce 384 partial num/den pairs, emit num/den.
// ---------------------------------------------------------------------------
__global__ __launch_bounds__(256) void finalize_kernel(
    const double* __restrict__ partial_num,
    const double* __restrict__ partial_den,
    float* __restrict__ out) {
    __shared__ double s_red[8];
    const int tid = threadIdx.x;

    double n_local = 0.0, d_local = 0.0;
    for (int i = tid; i < BB; i += 256) {
        n_local += partial_num[i];
        d_local += partial_den[i];
    }
    for (int off = 32; off > 0; off >>= 1) {
        n_local += __shfl_down(n_local, off, 64);
        d_local += __shfl_down(d_local, off, 64);
    }
    const int lane = tid & 63, wid = tid >> 6;
    if (lane == 0) { s_red[wid] = n_local; s_red[4 + wid] = d_local; }
    __syncthreads();

    if (tid == 0) {
        double num = (s_red[0] + s_red[1]) + (s_red[2] + s_red[3]);
        double den = (s_red[4] + s_red[5]) + (s_red[6] + s_red[7]);
        out[0] = (den > 0.0) ? (float)(num / den) : 0.0f;
    }
}

extern "C" void kernel_launch(void* const* d_in, const int* in_sizes, int n_in,
                              void* d_out, int out_size, void* d_ws, size_t ws_size,
                              hipStream_t stream) {
    const float* x = (const float*)d_in[0];
    const int* labels = (const int*)d_in[1];
    float* out = (float*)d_out;

    double* partial_num = (double*)d_ws;
    double* partial_den = partial_num + BB;

    triplet_fused_kernel<<<NBLK, NT, 0, stream>>>(x, labels, partial_num, partial_den);
    finalize_kernel<<<1, 256, 0, stream>>>(partial_num, partial_den, out);
}